// Round 2
// baseline (1370.066 us; speedup 1.0000x reference)
//
#include <hip/hip_runtime.h>
#include <stdint.h>

// ---------------------------------------------------------------------------
// AVAttention — ROUND 7: fuse the g-transpose into the q-projection.
// New kernel qproj_fused: 8 waves (2m x 4n), BM=128, BN=512 (full N), BK=32.
//   A = g[z][2560][2048] read DIRECTLY (strided): lane loads its fragment's
//       8 k-values as 8 coalesced dwords -> in-register fp32->bf16 pack.
//       Same lane->element mapping as the proven LDS path (fr=lane&15,
//       fk=(lane>>4)*8). A is read exactly ONCE from HBM (grid 16m x 16z,
//       1 block/CU).
//   B = WqT staged via global_load_lds, double-buffered, ONE barrier/K-step.
// Removes: transpose_cvt(g) (503 MB traffic) + old q-proj mfma_gemm (4x
// A-multiplicity). Everything else unchanged from round 6.
// d_out arena: phb@0 | k@16MB | vT@32MB | sc@48MB; final GEMM overwrites all.
// ---------------------------------------------------------------------------

typedef __attribute__((ext_vector_type(4))) float f32x4;
typedef __attribute__((ext_vector_type(8))) short bf16x8;

#define AS1 __attribute__((address_space(1)))
#define AS3 __attribute__((address_space(3)))

__device__ __forceinline__ ushort f2b(float x) {
    union { float f; uint32_t u; } v; v.f = x;
    uint32_t r = (v.u + 0x7FFFu + ((v.u >> 16) & 1u)) >> 16;
    return (ushort)r;
}
__device__ __forceinline__ float b2f(ushort u) {
    union { uint32_t u; float f; } v; v.u = ((uint32_t)u) << 16;
    return v.f;
}

__device__ __forceinline__ void gload16(const void* g, void* l) {
    __builtin_amdgcn_global_load_lds((const AS1 uint32_t*)g,
                                     (AS3 uint32_t*)l, 16, 0, 0);
}

// flag: 1 = inputs bf16, 0 = fp32.
__global__ void sniff_dtype(const uint32_t* __restrict__ ph, int* __restrict__ flag)
{
    if (threadIdx.x == 0 && blockIdx.x == 0) {
        int cnt = 0;
        for (int i = 0; i < 64; ++i) {
            uint32_t e = (ph[i] >> 7) & 0xFFu;
            if (e >= 90u && e <= 140u) ++cnt;
        }
        *flag = (cnt >= 40) ? 1 : 0;
    }
}

// ---------------- prep kernels (memory-bound, cheap) -----------------------

__global__ __launch_bounds__(256)
void cvt_bias(const void* __restrict__ src, float* __restrict__ dst, int n,
              const int* __restrict__ flag)
{
    int i = blockIdx.x * 256 + threadIdx.x;
    if (i >= n) return;
    dst[i] = (*flag == 0) ? ((const float*)src)[i]
                          : b2f(((const ushort*)src)[i]);
}

__global__ __launch_bounds__(256)
void cvt_bf16(const void* __restrict__ src, ushort* __restrict__ dst, int n8,
              const int* __restrict__ flag)
{
    int i = blockIdx.x * 256 + threadIdx.x;
    if (i >= n8) return;
    if (*flag == 0) {
        const float4* s = (const float4*)src;
        float4 a = s[2 * i], b = s[2 * i + 1];
        uint4 o;
        o.x = (uint32_t)f2b(a.x) | ((uint32_t)f2b(a.y) << 16);
        o.y = (uint32_t)f2b(a.z) | ((uint32_t)f2b(a.w) << 16);
        o.z = (uint32_t)f2b(b.x) | ((uint32_t)f2b(b.y) << 16);
        o.w = (uint32_t)f2b(b.z) | ((uint32_t)f2b(b.w) << 16);
        ((uint4*)dst)[i] = o;
    } else {
        ((uint4*)dst)[i] = ((const uint4*)src)[i];
    }
}

// src [z][R][Cc] (fp32/bf16) -> dst [z][Cc][R] bf16. 32x32 LDS tile.
// (Still used for the small weight matrices only.)
__global__ __launch_bounds__(256)
void transpose_cvt(const void* __restrict__ src, ushort* __restrict__ dst,
                   int R, int Cc, long sbat, long dbat,
                   const int* __restrict__ flag)
{
    __shared__ ushort tile[32][33];
    const bool isf32 = (*flag == 0);
    const int r0 = blockIdx.y * 32, c0 = blockIdx.x * 32;
    const int tr = threadIdx.x >> 3;
    const int tc4 = (threadIdx.x & 7) * 4;

    const char* sb = (const char*)src + (size_t)blockIdx.z * sbat * (isf32 ? 4 : 2);
    if (isf32) {
        const float4* s = (const float4*)((const float*)sb + (size_t)(r0 + tr) * Cc + c0 + tc4);
        float4 v = *s;
        tile[tr][tc4 + 0] = f2b(v.x); tile[tr][tc4 + 1] = f2b(v.y);
        tile[tr][tc4 + 2] = f2b(v.z); tile[tr][tc4 + 3] = f2b(v.w);
    } else {
        const ushort4* s = (const ushort4*)((const ushort*)sb + (size_t)(r0 + tr) * Cc + c0 + tc4);
        ushort4 v = *s;
        tile[tr][tc4 + 0] = v.x; tile[tr][tc4 + 1] = v.y;
        tile[tr][tc4 + 2] = v.z; tile[tr][tc4 + 3] = v.w;
    }
    __syncthreads();
    ushort4 o;
    o.x = tile[tc4 + 0][tr]; o.y = tile[tc4 + 1][tr];
    o.z = tile[tc4 + 2][tr]; o.w = tile[tc4 + 3][tr];
    *(ushort4*)(dst + (size_t)blockIdx.z * dbat + (size_t)(c0 + tr) * R + r0 + tc4) = o;
}

// ---------------- fused q-projection ---------------------------------------
// q[z][m][n] = sum_k g[z][k][m] * WqT[n][k] + bq[n]
// M=2048, N=512 (full, BN=512), K=2560. 512 thr = 8 waves (2 wr x 4 wc).
// A direct-from-global (transpose free in register orientation); B via
// global_load_lds into double-buffered LDS, 1 barrier per K-step.
__global__ __launch_bounds__(512, 2)
void qproj_fused(const void* __restrict__ G, const ushort* __restrict__ WqT,
                 ushort* __restrict__ Q, const float* __restrict__ bq,
                 const int* __restrict__ flag)
{
    __shared__ ushort Bs[2][512 * 32];
    const bool isf32 = (*flag == 0);
    const int tid = threadIdx.x;
    const int lane = tid & 63;
    const int wave = tid >> 6;
    const int wr = wave >> 2, wc = wave & 3;
    const int fr = lane & 15, fkg = lane >> 4;     // fk = fkg*8
    const int m0 = blockIdx.x * 128;
    const int bz = blockIdx.y;

    const float*  gzf = (const float*)G  + (size_t)bz * 2560 * 2048;
    const ushort* gzh = (const ushort*)G + (size_t)bz * 2560 * 2048;
    const int mcol = m0 + wr * 64 + fr;

    // A element indices: idx[j] -> g[kt*32 + fkg*8 + j][mcol]  (+ mi*16 cols)
    uint32_t idx[8];
#pragma unroll
    for (int j = 0; j < 8; ++j)
        idx[j] = (uint32_t)(fkg * 8 + j) * 2048u + (uint32_t)mcol;

    // B staging: thread covers rows (tid>>2)+p*128, k-octet (tid&3)*8
    const ushort* gB[4];
#pragma unroll
    for (int p = 0; p < 4; ++p)
        gB[p] = WqT + (size_t)((tid >> 2) + p * 128) * 2560 + (tid & 3) * 8;

    float  rawf[4][8];
    ushort rawh[4][8];

    // ---- prefetch A(0) ----
    if (isf32) {
#pragma unroll
        for (int j = 0; j < 8; ++j)
#pragma unroll
            for (int mi = 0; mi < 4; ++mi)
                rawf[mi][j] = gzf[idx[j] + mi * 16];
    } else {
#pragma unroll
        for (int j = 0; j < 8; ++j)
#pragma unroll
            for (int mi = 0; mi < 4; ++mi)
                rawh[mi][j] = gzh[idx[j] + mi * 16];
    }
#pragma unroll
    for (int j = 0; j < 8; ++j) idx[j] += 65536u;   // 32 k-rows * 2048

    // ---- stage B(0) -> buf 0 ----
#pragma unroll
    for (int p = 0; p < 4; ++p)
        gload16(gB[p], &Bs[0][tid * 8 + p * 4096]);

    f32x4 acc[4][8] = {};

    for (int kt = 0; kt < 80; ++kt) {
        __syncthreads();   // drains vmcnt: B(kt) staged, raw(kt) landed

        // cvt raw(kt) -> af  (RNE, matches f2b path numerics)
        bf16x8 af[4];
        if (isf32) {
#pragma unroll
            for (int mi = 0; mi < 4; ++mi) {
                union { bf16x8 v; uint32_t u[4]; } w;
#pragma unroll
                for (int p = 0; p < 4; ++p)
                    w.u[p] = (uint32_t)f2b(rawf[mi][2 * p]) |
                             ((uint32_t)f2b(rawf[mi][2 * p + 1]) << 16);
                af[mi] = w.v;
            }
        } else {
#pragma unroll
            for (int mi = 0; mi < 4; ++mi) {
                union { bf16x8 v; uint32_t u[4]; } w;
#pragma unroll
                for (int p = 0; p < 4; ++p)
                    w.u[p] = (uint32_t)rawh[mi][2 * p] |
                             ((uint32_t)rawh[mi][2 * p + 1] << 16);
                af[mi] = w.v;
            }
        }

        if (kt + 1 < 80) {
            // prefetch A(kt+1) into raw
            if (isf32) {
#pragma unroll
                for (int j = 0; j < 8; ++j)
#pragma unroll
                    for (int mi = 0; mi < 4; ++mi)
                        rawf[mi][j] = gzf[idx[j] + mi * 16];
            } else {
#pragma unroll
                for (int j = 0; j < 8; ++j)
#pragma unroll
                    for (int mi = 0; mi < 4; ++mi)
                        rawh[mi][j] = gzh[idx[j] + mi * 16];
            }
#pragma unroll
            for (int j = 0; j < 8; ++j) idx[j] += 65536u;
            // stage B(kt+1) -> other buffer
#pragma unroll
            for (int p = 0; p < 4; ++p)
                gload16(gB[p] + (kt + 1) * 32,
                        &Bs[(kt + 1) & 1][tid * 8 + p * 4096]);
        }

        // read B fragments for this K-step
        const ushort* pbb = &Bs[kt & 1][(wc * 128 + fr) * 32 + fkg * 8];
        bf16x8 bfr[8];
#pragma unroll
        for (int ni = 0; ni < 8; ++ni)
            bfr[ni] = *(const bf16x8*)(pbb + (size_t)ni * 16 * 32);

#pragma unroll
        for (int mi = 0; mi < 4; ++mi)
#pragma unroll
            for (int ni = 0; ni < 8; ++ni)
                acc[mi][ni] = __builtin_amdgcn_mfma_f32_16x16x32_bf16(
                    af[mi], bfr[ni], acc[mi][ni], 0, 0, 0);
    }

    // epilogue: C/D layout col=lane&15, row=(lane>>4)*4+reg
    ushort* qp = Q + (size_t)bz * 2048 * 512;
#pragma unroll
    for (int ni = 0; ni < 8; ++ni) {
        const int n = wc * 128 + ni * 16 + fr;
        const float bv = bq[n];
#pragma unroll
        for (int mi = 0; mi < 4; ++mi) {
            f32x4 v = acc[mi][ni];
            const int m = m0 + wr * 64 + mi * 16 + fkg * 4;
#pragma unroll
            for (int r = 0; r < 4; ++r)
                qp[(size_t)(m + r) * 512 + n] = f2b(v[r] + bv);
        }
    }
}

// ---------------- MFMA GEMM (m97 structure, proven) ------------------------
template<int STORE>
__global__ __launch_bounds__(256)
void mfma_gemm(const ushort* __restrict__ A, const ushort* __restrict__ Bt,
               void* __restrict__ C, const float* __restrict__ bias,
               int M, int N, int K,
               long Abat, long Bbat, long Cbat, long ldc, float scale)
{
    __shared__ ushort As[128 * 32];
    __shared__ ushort Bs[128 * 32];

    const int tid = threadIdx.x;
    const int lane = tid & 63;
    const int wave = tid >> 6;
    const int wr = wave >> 1, wc = wave & 1;
    const int m0 = blockIdx.y * 128, n0 = blockIdx.x * 128;

    const ushort* Ab = A + (size_t)blockIdx.z * Abat;
    const ushort* Bb = Bt + (size_t)blockIdx.z * Bbat;

    const int srow = tid >> 2;
    const int scol = (tid & 3) * 8;
    const ushort* gA = Ab + (size_t)(m0 + srow) * K + scol;
    const ushort* gB = Bb + (size_t)(n0 + srow) * K + scol;
    const size_t rowskip = (size_t)64 * K;
    ushort* lA = As + tid * 8;
    ushort* lB = Bs + tid * 8;

    const int fr = lane & 15;
    const int fk = (lane >> 4) * 8;
    const ushort* pa = As + (size_t)(wr * 64 + fr) * 32 + fk;
    const ushort* pb = Bs + (size_t)(wc * 64 + fr) * 32 + fk;

    f32x4 acc[4][4] = {};

    for (int k0 = 0; k0 < K; k0 += 32) {
        gload16(gA, lA);
        gload16(gA + rowskip, lA + 2048);
        gload16(gB, lB);
        gload16(gB + rowskip, lB + 2048);
        gA += 32; gB += 32;
        __syncthreads();

        bf16x8 af[4], bf[4];
#pragma unroll
        for (int i = 0; i < 4; ++i) af[i] = *(const bf16x8*)(pa + (size_t)i * 16 * 32);
#pragma unroll
        for (int i = 0; i < 4; ++i) bf[i] = *(const bf16x8*)(pb + (size_t)i * 16 * 32);
#pragma unroll
        for (int mi = 0; mi < 4; ++mi)
#pragma unroll
            for (int ni = 0; ni < 4; ++ni)
                acc[mi][ni] = __builtin_amdgcn_mfma_f32_16x16x32_bf16(
                    af[mi], bf[ni], acc[mi][ni], 0, 0, 0);
        __syncthreads();
    }

    const int nb = n0 + wc * 64;
    const int mb = m0 + wr * 64 + (lane >> 4) * 4;
#pragma unroll
    for (int ni = 0; ni < 4; ++ni) {
        const int n = nb + ni * 16 + fr;
        const float bv = bias ? bias[n] : 0.f;
#pragma unroll
        for (int mi = 0; mi < 4; ++mi) {
            f32x4 v = acc[mi][ni];
            const int m = mb + mi * 16;
            if (STORE == 0) {
                ushort* Cc = (ushort*)C + (size_t)blockIdx.z * Cbat;
#pragma unroll
                for (int r = 0; r < 4; ++r)
                    Cc[(size_t)(m + r) * ldc + n] = f2b(v[r] * scale + bv);
            } else if (STORE == 1) {
                ushort* Cc = (ushort*)C + (size_t)blockIdx.z * Cbat;
                ushort4 o;
                o.x = f2b(v[0] * scale + bv); o.y = f2b(v[1] * scale + bv);
                o.z = f2b(v[2] * scale + bv); o.w = f2b(v[3] * scale + bv);
                *(ushort4*)(Cc + (size_t)n * ldc + m) = o;
            } else {
                float* Cf = (float*)C + (size_t)blockIdx.z * Cbat;
                float4 o = { v[0] * scale + bv, v[1] * scale + bv,
                             v[2] * scale + bv, v[3] * scale + bv };
                *(float4*)(Cf + (size_t)(n & 63) * (20 * 2048)
                              + (size_t)(n >> 6) * 2048 + m) = o;
            }
        }
    }
}

// ---------------- masked softmax (unchanged, proven) -----------------------
__global__ __launch_bounds__(256)
void softmax_mask(ushort* __restrict__ sc, const int* __restrict__ lengths)
{
    const int t = blockIdx.x, b = blockIdx.y, tid = threadIdx.x;
    const bool is64 = (lengths[1] == 0 && lengths[3] == 0 && lengths[5] == 0);
    const int len = is64 ? lengths[2 * b] : lengths[b];

    ushort* row = sc + ((size_t)b * 2048 + t) * 1024;
    const int s0 = tid * 4;
    uint2 pk = *(const uint2*)(row + s0);
    ushort u[4] = { (ushort)(pk.x & 0xffff), (ushort)(pk.x >> 16),
                    (ushort)(pk.y & 0xffff), (ushort)(pk.y >> 16) };
    float v[4];
    float mx = -INFINITY;
#pragma unroll
    for (int j = 0; j < 4; ++j) {
        v[j] = (s0 + j < len) ? b2f(u[j]) : -INFINITY;
        mx = fmaxf(mx, v[j]);
    }
    for (int off = 32; off > 0; off >>= 1) mx = fmaxf(mx, __shfl_xor(mx, off));
    __shared__ float redm[4], reds[4];
    const int w = tid >> 6;
    if ((tid & 63) == 0) redm[w] = mx;
    __syncthreads();
    mx = fmaxf(fmaxf(redm[0], redm[1]), fmaxf(redm[2], redm[3]));

    float e[4]; float sum = 0.f;
#pragma unroll
    for (int j = 0; j < 4; ++j) { e[j] = __expf(v[j] - mx); sum += e[j]; }
    for (int off = 32; off > 0; off >>= 1) sum += __shfl_xor(sum, off);
    if ((tid & 63) == 0) reds[w] = sum;
    __syncthreads();
    sum = reds[0] + reds[1] + reds[2] + reds[3];
    const float inv = 1.0f / sum;

    ushort o[4];
#pragma unroll
    for (int j = 0; j < 4; ++j) o[j] = f2b(e[j] * inv);
    uint2 opk;
    opk.x = (uint32_t)o[0] | ((uint32_t)o[1] << 16);
    opk.y = (uint32_t)o[2] | ((uint32_t)o[3] << 16);
    *(uint2*)(row + s0) = opk;
}

// ---------------------------------------------------------------------------
extern "C" void kernel_launch(void* const* d_in, const int* in_sizes, int n_in,
                              void* d_out, int out_size, void* d_ws, size_t ws_size,
                              hipStream_t stream)
{
    const void* ph   = d_in[0];   // [16,1024,512]
    const void* g    = d_in[1];   // [16,2560,2048]
    const int*  len  = (const int*)d_in[2];
    const void* Wk   = d_in[3];   // [512,512]  W[k][n]
    const void* bk   = d_in[4];
    const void* Wv   = d_in[5];
    const void* bv   = d_in[6];
    const void* Wq   = d_in[7];   // [2560,512]
    const void* bq   = d_in[8];
    const void* Wmel = d_in[9];   // [512,1280]
    const void* bmel = d_in[10];
    void* out = d_out;            // [16,64,20,2048] fp32

    // ---- workspace ----
    char* ws = (char*)d_ws;
    size_t off = 0;
    auto alloc = [&](size_t bytes) -> char* {
        char* p = ws + off;
        off += (bytes + 255) & ~(size_t)255;
        return p;
    };
    int*    flag  = (int*)alloc(256);
    float*  bkf   = (float*)alloc(512 * 4);
    float*  bvf   = (float*)alloc(512 * 4);
    float*  bqf   = (float*)alloc(512 * 4);
    float*  bmelf = (float*)alloc(1280 * 4);
    ushort* WkT   = (ushort*)alloc((size_t)512 * 512 * 2);
    ushort* WvT   = (ushort*)alloc((size_t)512 * 512 * 2);
    ushort* WqT   = (ushort*)alloc((size_t)512 * 2560 * 2);
    ushort* WmelT = (ushort*)alloc((size_t)1280 * 512 * 2);
    ushort* qval  = (ushort*)alloc((size_t)16 * 2048 * 512 * 2);  // q, then val

    // ---- d_out arena ----
    char* dob = (char*)d_out;
    ushort* phb = (ushort*)dob;                          // [16][1024][512]
    ushort* kbf = (ushort*)(dob + 16777216);             // [16][1024][512]
    ushort* vT  = (ushort*)(dob + 33554432);             // [16][512][1024]
    ushort* sc  = (ushort*)(dob + 50331648);             // [16][2048][1024]

    sniff_dtype<<<1, 64, 0, stream>>>((const uint32_t*)ph, flag);

    // prep: weight transposes + bias/ph conversions (g transpose REMOVED)
    transpose_cvt<<<dim3(16, 16, 1), 256, 0, stream>>>(Wk, WkT, 512, 512, 0, 0, flag);
    transpose_cvt<<<dim3(16, 16, 1), 256, 0, stream>>>(Wv, WvT, 512, 512, 0, 0, flag);
    transpose_cvt<<<dim3(16, 80, 1), 256, 0, stream>>>(Wq, WqT, 2560, 512, 0, 0, flag);
    transpose_cvt<<<dim3(40, 16, 1), 256, 0, stream>>>(Wmel, WmelT, 512, 1280, 0, 0, flag);
    cvt_bias<<<2, 256, 0, stream>>>(bk, bkf, 512, flag);
    cvt_bias<<<2, 256, 0, stream>>>(bv, bvf, 512, flag);
    cvt_bias<<<2, 256, 0, stream>>>(bq, bqf, 512, flag);
    cvt_bias<<<5, 256, 0, stream>>>(bmel, bmelf, 1280, flag);
    cvt_bf16<<<4096, 256, 0, stream>>>(ph, phb, 1048576, flag);

    // q[b][t][d] = g[b][:,t] . Wq[:,d] + bq  — fused transpose+GEMM
    qproj_fused<<<dim3(16, 16), 512, 0, stream>>>(g, WqT, qval, bqf, flag);

    // k[b][s][d] = ph_bf @ WkT^T + bk
    mfma_gemm<0><<<dim3(4, 8, 16), dim3(256), 0, stream>>>(
        phb, WkT, kbf, bkf, 1024, 512, 512,
        1024L * 512, 0, 1024L * 512, 512, 1.f);
    // vT[b][d][s] = (ph_bf @ WvT^T + bv)^T
    mfma_gemm<1><<<dim3(4, 8, 16), dim3(256), 0, stream>>>(
        phb, WvT, vT, bvf, 1024, 512, 512,
        1024L * 512, 0, 512L * 1024, 1024, 1.f);

    // sc[b][t][s] = q @ k^T / sqrt(512)
    mfma_gemm<0><<<dim3(8, 16, 16), dim3(256), 0, stream>>>(
        qval, kbf, sc, nullptr, 2048, 1024, 512,
        2048L * 512, 1024L * 512, 2048L * 1024, 1024, 0.044194173824159216f);

    softmax_mask<<<dim3(2048, 16), 256, 0, stream>>>(sc, len);

    // val[b][t][d] = P @ vT^T — overwrites dead q
    mfma_gemm<0><<<dim3(4, 16, 16), dim3(256), 0, stream>>>(
        sc, vT, qval, nullptr, 2048, 512, 1024,
        2048L * 1024, 512L * 1024, 2048L * 512, 512, 1.f);

    // out[b][n&63][n>>6][t] = val @ WmelT^T + bmel  (fp32 final)
    mfma_gemm<2><<<dim3(10, 16, 16), dim3(256), 0, stream>>>(
        qval, WmelT, out, bmelf, 2048, 1280, 512,
        2048L * 512, 0, 64L * 20 * 2048, 0, 1.f);
}

// Round 3
// 1343.440 us; speedup vs baseline: 1.0198x; 1.0198x over previous
//
#include <hip/hip_runtime.h>
#include <stdint.h>

// ---------------------------------------------------------------------------
// AVAttention — ROUND 8: revert to round-6 proven pipeline; replace the
// g-transpose + q-GEMM pair with qproj_fused2 (LDS-transpose A-staging).
// Round-7 post-mortem: register-transpose A (32 scalar dwords/lane/K-step)
// at 1 block/CU was latency-bound (MfmaUtil 5%). Fix: A through LDS
// (coalesced row loads + transposed ds_write_b64), BN=256 -> 512 blocks
// (2/CU), 4-wave m97-like block structure.
// d_out arena: phb@0 | k@16MB | vT@32MB | sc@48MB; final GEMM overwrites all.
// ---------------------------------------------------------------------------

typedef __attribute__((ext_vector_type(4))) float f32x4;
typedef __attribute__((ext_vector_type(8))) short bf16x8;

#define AS1 __attribute__((address_space(1)))
#define AS3 __attribute__((address_space(3)))

__device__ __forceinline__ ushort f2b(float x) {
    union { float f; uint32_t u; } v; v.f = x;
    uint32_t r = (v.u + 0x7FFFu + ((v.u >> 16) & 1u)) >> 16;
    return (ushort)r;
}
__device__ __forceinline__ float b2f(ushort u) {
    union { uint32_t u; float f; } v; v.u = ((uint32_t)u) << 16;
    return v.f;
}

__device__ __forceinline__ void gload16(const void* g, void* l) {
    __builtin_amdgcn_global_load_lds((const AS1 uint32_t*)g,
                                     (AS3 uint32_t*)l, 16, 0, 0);
}

// flag: 1 = inputs bf16, 0 = fp32.
__global__ void sniff_dtype(const uint32_t* __restrict__ ph, int* __restrict__ flag)
{
    if (threadIdx.x == 0 && blockIdx.x == 0) {
        int cnt = 0;
        for (int i = 0; i < 64; ++i) {
            uint32_t e = (ph[i] >> 7) & 0xFFu;
            if (e >= 90u && e <= 140u) ++cnt;
        }
        *flag = (cnt >= 40) ? 1 : 0;
    }
}

// ---------------- prep kernels (memory-bound, cheap) -----------------------

__global__ __launch_bounds__(256)
void cvt_bias(const void* __restrict__ src, float* __restrict__ dst, int n,
              const int* __restrict__ flag)
{
    int i = blockIdx.x * 256 + threadIdx.x;
    if (i >= n) return;
    dst[i] = (*flag == 0) ? ((const float*)src)[i]
                          : b2f(((const ushort*)src)[i]);
}

__global__ __launch_bounds__(256)
void cvt_bf16(const void* __restrict__ src, ushort* __restrict__ dst, int n8,
              const int* __restrict__ flag)
{
    int i = blockIdx.x * 256 + threadIdx.x;
    if (i >= n8) return;
    if (*flag == 0) {
        const float4* s = (const float4*)src;
        float4 a = s[2 * i], b = s[2 * i + 1];
        uint4 o;
        o.x = (uint32_t)f2b(a.x) | ((uint32_t)f2b(a.y) << 16);
        o.y = (uint32_t)f2b(a.z) | ((uint32_t)f2b(a.w) << 16);
        o.z = (uint32_t)f2b(b.x) | ((uint32_t)f2b(b.y) << 16);
        o.w = (uint32_t)f2b(b.z) | ((uint32_t)f2b(b.w) << 16);
        ((uint4*)dst)[i] = o;
    } else {
        ((uint4*)dst)[i] = ((const uint4*)src)[i];
    }
}

// src [z][R][Cc] (fp32/bf16) -> dst [z][Cc][R] bf16. 32x32 LDS tile.
// (Weight matrices only.)
__global__ __launch_bounds__(256)
void transpose_cvt(const void* __restrict__ src, ushort* __restrict__ dst,
                   int R, int Cc, long sbat, long dbat,
                   const int* __restrict__ flag)
{
    __shared__ ushort tile[32][33];
    const bool isf32 = (*flag == 0);
    const int r0 = blockIdx.y * 32, c0 = blockIdx.x * 32;
    const int tr = threadIdx.x >> 3;
    const int tc4 = (threadIdx.x & 7) * 4;

    const char* sb = (const char*)src + (size_t)blockIdx.z * sbat * (isf32 ? 4 : 2);
    if (isf32) {
        const float4* s = (const float4*)((const float*)sb + (size_t)(r0 + tr) * Cc + c0 + tc4);
        float4 v = *s;
        tile[tr][tc4 + 0] = f2b(v.x); tile[tr][tc4 + 1] = f2b(v.y);
        tile[tr][tc4 + 2] = f2b(v.z); tile[tr][tc4 + 3] = f2b(v.w);
    } else {
        const ushort4* s = (const ushort4*)((const ushort*)sb + (size_t)(r0 + tr) * Cc + c0 + tc4);
        ushort4 v = *s;
        tile[tr][tc4 + 0] = v.x; tile[tr][tc4 + 1] = v.y;
        tile[tr][tc4 + 2] = v.z; tile[tr][tc4 + 3] = v.w;
    }
    __syncthreads();
    ushort4 o;
    o.x = tile[tc4 + 0][tr]; o.y = tile[tc4 + 1][tr];
    o.z = tile[tc4 + 2][tr]; o.w = tile[tc4 + 3][tr];
    *(ushort4*)(dst + (size_t)blockIdx.z * dbat + (size_t)(c0 + tr) * R + r0 + tc4) = o;
}

// ---------------- fused q-projection v2 ------------------------------------
// q[z][m][n] = sum_k g[z][k][m] * WqT[n][k] + bq[n]
// M=2048, N=512, K=2560. BM=128, BN=256, BK=32; 256 thr = 4 waves (2m x 2n);
// grid (2 n, 16 m, 16 z) = 512 blocks = 2/CU.
// A-staging: coalesced row loads of g (lane sweeps m), in-register fp32->bf16
// pack, transposed ds_write_b64 into As[128m][40k] (pad 8 keeps 16B align).
// B-staging: proven global_load_lds scheme into linear Bs[256n][32k].
__global__ __launch_bounds__(256)
void qproj_fused2(const void* __restrict__ G, const ushort* __restrict__ WqT,
                  ushort* __restrict__ Q, const float* __restrict__ bq,
                  const int* __restrict__ flag)
{
    __shared__ __align__(16) ushort As[128 * 40];   // [m][k], stride 40 (pad 8)
    __shared__ __align__(16) ushort Bs[256 * 32];   // [n][k] linear (gload_lds)

    const bool isf32 = (*flag == 0);
    const int tid = threadIdx.x;
    const int lane = tid & 63;
    const int wave = tid >> 6;
    const int wr = wave >> 1, wc = wave & 1;   // wave tile: 64m x 128n
    const int n0 = blockIdx.x * 256;
    const int m0 = blockIdx.y * 128;
    const int bz = blockIdx.z;

    const float*  gzf = (const float*)G  + (size_t)bz * 2560 * 2048;
    const ushort* gzh = (const ushort*)G + (size_t)bz * 2560 * 2048;

    // B staging: thread covers rows (tid>>2) + {0,64,128,192}, k-octet (tid&3)*8
    const ushort* gB = WqT + (size_t)(n0 + (tid >> 2)) * 2560 + (tid & 3) * 8;
    ushort* lB = Bs + tid * 8;                 // byte tid*16 (uniform+lane*16)
    const size_t brs = (size_t)64 * 2560;

    const int fr = lane & 15, fkg = lane >> 4;
    const ushort* pa = As + (size_t)(wr * 64 + fr) * 40 + fkg * 8;
    const ushort* pb = Bs + (size_t)(wc * 128 + fr) * 32 + fkg * 8;

    f32x4 acc[4][8] = {};

    for (int kt = 0; kt < 80; ++kt) {
        const int k0 = kt * 32;
        // ---- stage B (16KB) : 4 x global_load_lds ----
        gload16(gB,           lB);
        gload16(gB + brs,     lB + 2048);
        gload16(gB + 2 * brs, lB + 4096);
        gload16(gB + 3 * brs, lB + 6144);
        gB += 32;
        // ---- stage A (transposed): 16 coalesced scalars -> 4 ds_write_b64 ----
#pragma unroll
        for (int r = 0; r < 4; ++r) {
            const int m  = lane + 64 * (r & 1);
            const int kb = (wave + 4 * (r >> 1)) * 4;
            ushort4 o;
            if (isf32) {
                const float* p = gzf + (size_t)(k0 + kb) * 2048 + m0 + m;
                o.x = f2b(p[0]);    o.y = f2b(p[2048]);
                o.z = f2b(p[4096]); o.w = f2b(p[6144]);
            } else {
                const ushort* p = gzh + (size_t)(k0 + kb) * 2048 + m0 + m;
                o.x = p[0];    o.y = p[2048];
                o.z = p[4096]; o.w = p[6144];
            }
            *(ushort4*)(As + (size_t)m * 40 + kb) = o;
        }
        __syncthreads();   // drains lgkm (A writes) + vmcnt (B gload_lds)

        bf16x8 af[4], bf[8];
#pragma unroll
        for (int i = 0; i < 4; ++i) af[i] = *(const bf16x8*)(pa + (size_t)i * 16 * 40);
#pragma unroll
        for (int i = 0; i < 8; ++i) bf[i] = *(const bf16x8*)(pb + (size_t)i * 16 * 32);
#pragma unroll
        for (int mi = 0; mi < 4; ++mi)
#pragma unroll
            for (int ni = 0; ni < 8; ++ni)
                acc[mi][ni] = __builtin_amdgcn_mfma_f32_16x16x32_bf16(
                    af[mi], bf[ni], acc[mi][ni], 0, 0, 0);
        __syncthreads();   // protect LDS from next-iter staging
    }

    // epilogue: C/D layout col=lane&15, row=(lane>>4)*4+reg
    ushort* qp = Q + (size_t)bz * 2048 * 512;
    const int mb = m0 + wr * 64 + fkg * 4;
#pragma unroll
    for (int ni = 0; ni < 8; ++ni) {
        const int n = n0 + wc * 128 + ni * 16 + fr;
        const float bv = bq[n];
#pragma unroll
        for (int mi = 0; mi < 4; ++mi) {
            f32x4 v = acc[mi][ni];
            const int m = mb + mi * 16;
#pragma unroll
            for (int r = 0; r < 4; ++r)
                qp[(size_t)(m + r) * 512 + n] = f2b(v[r] + bv);
        }
    }
}

// ---------------- MFMA GEMM (m97 structure, proven) ------------------------
template<int STORE>
__global__ __launch_bounds__(256)
void mfma_gemm(const ushort* __restrict__ A, const ushort* __restrict__ Bt,
               void* __restrict__ C, const float* __restrict__ bias,
               int M, int N, int K,
               long Abat, long Bbat, long Cbat, long ldc, float scale)
{
    __shared__ __align__(16) ushort As[128 * 32];
    __shared__ __align__(16) ushort Bs[128 * 32];

    const int tid = threadIdx.x;
    const int lane = tid & 63;
    const int wave = tid >> 6;
    const int wr = wave >> 1, wc = wave & 1;
    const int m0 = blockIdx.y * 128, n0 = blockIdx.x * 128;

    const ushort* Ab = A + (size_t)blockIdx.z * Abat;
    const ushort* Bb = Bt + (size_t)blockIdx.z * Bbat;

    const int srow = tid >> 2;
    const int scol = (tid & 3) * 8;
    const ushort* gA = Ab + (size_t)(m0 + srow) * K + scol;
    const ushort* gB = Bb + (size_t)(n0 + srow) * K + scol;
    const size_t rowskip = (size_t)64 * K;
    ushort* lA = As + tid * 8;
    ushort* lB = Bs + tid * 8;

    const int fr = lane & 15;
    const int fk = (lane >> 4) * 8;
    const ushort* pa = As + (size_t)(wr * 64 + fr) * 32 + fk;
    const ushort* pb = Bs + (size_t)(wc * 64 + fr) * 32 + fk;

    f32x4 acc[4][4] = {};

    for (int k0 = 0; k0 < K; k0 += 32) {
        gload16(gA, lA);
        gload16(gA + rowskip, lA + 2048);
        gload16(gB, lB);
        gload16(gB + rowskip, lB + 2048);
        gA += 32; gB += 32;
        __syncthreads();

        bf16x8 af[4], bf[4];
#pragma unroll
        for (int i = 0; i < 4; ++i) af[i] = *(const bf16x8*)(pa + (size_t)i * 16 * 32);
#pragma unroll
        for (int i = 0; i < 4; ++i) bf[i] = *(const bf16x8*)(pb + (size_t)i * 16 * 32);
#pragma unroll
        for (int mi = 0; mi < 4; ++mi)
#pragma unroll
            for (int ni = 0; ni < 4; ++ni)
                acc[mi][ni] = __builtin_amdgcn_mfma_f32_16x16x32_bf16(
                    af[mi], bf[ni], acc[mi][ni], 0, 0, 0);
        __syncthreads();
    }

    const int nb = n0 + wc * 64;
    const int mb = m0 + wr * 64 + (lane >> 4) * 4;
#pragma unroll
    for (int ni = 0; ni < 4; ++ni) {
        const int n = nb + ni * 16 + fr;
        const float bv = bias ? bias[n] : 0.f;
#pragma unroll
        for (int mi = 0; mi < 4; ++mi) {
            f32x4 v = acc[mi][ni];
            const int m = mb + mi * 16;
            if (STORE == 0) {
                ushort* Cc = (ushort*)C + (size_t)blockIdx.z * Cbat;
#pragma unroll
                for (int r = 0; r < 4; ++r)
                    Cc[(size_t)(m + r) * ldc + n] = f2b(v[r] * scale + bv);
            } else if (STORE == 1) {
                ushort* Cc = (ushort*)C + (size_t)blockIdx.z * Cbat;
                ushort4 o;
                o.x = f2b(v[0] * scale + bv); o.y = f2b(v[1] * scale + bv);
                o.z = f2b(v[2] * scale + bv); o.w = f2b(v[3] * scale + bv);
                *(ushort4*)(Cc + (size_t)n * ldc + m) = o;
            } else {
                float* Cf = (float*)C + (size_t)blockIdx.z * Cbat;
                float4 o = { v[0] * scale + bv, v[1] * scale + bv,
                             v[2] * scale + bv, v[3] * scale + bv };
                *(float4*)(Cf + (size_t)(n & 63) * (20 * 2048)
                              + (size_t)(n >> 6) * 2048 + m) = o;
            }
        }
    }
}

// ---------------- masked softmax (unchanged, proven) -----------------------
__global__ __launch_bounds__(256)
void softmax_mask(ushort* __restrict__ sc, const int* __restrict__ lengths)
{
    const int t = blockIdx.x, b = blockIdx.y, tid = threadIdx.x;
    const bool is64 = (lengths[1] == 0 && lengths[3] == 0 && lengths[5] == 0);
    const int len = is64 ? lengths[2 * b] : lengths[b];

    ushort* row = sc + ((size_t)b * 2048 + t) * 1024;
    const int s0 = tid * 4;
    uint2 pk = *(const uint2*)(row + s0);
    ushort u[4] = { (ushort)(pk.x & 0xffff), (ushort)(pk.x >> 16),
                    (ushort)(pk.y & 0xffff), (ushort)(pk.y >> 16) };
    float v[4];
    float mx = -INFINITY;
#pragma unroll
    for (int j = 0; j < 4; ++j) {
        v[j] = (s0 + j < len) ? b2f(u[j]) : -INFINITY;
        mx = fmaxf(mx, v[j]);
    }
    for (int off = 32; off > 0; off >>= 1) mx = fmaxf(mx, __shfl_xor(mx, off));
    __shared__ float redm[4], reds[4];
    const int w = tid >> 6;
    if ((tid & 63) == 0) redm[w] = mx;
    __syncthreads();
    mx = fmaxf(fmaxf(redm[0], redm[1]), fmaxf(redm[2], redm[3]));

    float e[4]; float sum = 0.f;
#pragma unroll
    for (int j = 0; j < 4; ++j) { e[j] = __expf(v[j] - mx); sum += e[j]; }
    for (int off = 32; off > 0; off >>= 1) sum += __shfl_xor(sum, off);
    if ((tid & 63) == 0) reds[w] = sum;
    __syncthreads();
    sum = reds[0] + reds[1] + reds[2] + reds[3];
    const float inv = 1.0f / sum;

    ushort o[4];
#pragma unroll
    for (int j = 0; j < 4; ++j) o[j] = f2b(e[j] * inv);
    uint2 opk;
    opk.x = (uint32_t)o[0] | ((uint32_t)o[1] << 16);
    opk.y = (uint32_t)o[2] | ((uint32_t)o[3] << 16);
    *(uint2*)(row + s0) = opk;
}

// ---------------------------------------------------------------------------
extern "C" void kernel_launch(void* const* d_in, const int* in_sizes, int n_in,
                              void* d_out, int out_size, void* d_ws, size_t ws_size,
                              hipStream_t stream)
{
    const void* ph   = d_in[0];   // [16,1024,512]
    const void* g    = d_in[1];   // [16,2560,2048]
    const int*  len  = (const int*)d_in[2];
    const void* Wk   = d_in[3];   // [512,512]  W[k][n]
    const void* bk   = d_in[4];
    const void* Wv   = d_in[5];
    const void* bv   = d_in[6];
    const void* Wq   = d_in[7];   // [2560,512]
    const void* bq   = d_in[8];
    const void* Wmel = d_in[9];   // [512,1280]
    const void* bmel = d_in[10];
    void* out = d_out;            // [16,64,20,2048] fp32

    // ---- workspace ----
    char* ws = (char*)d_ws;
    size_t off = 0;
    auto alloc = [&](size_t bytes) -> char* {
        char* p = ws + off;
        off += (bytes + 255) & ~(size_t)255;
        return p;
    };
    int*    flag  = (int*)alloc(256);
    float*  bkf   = (float*)alloc(512 * 4);
    float*  bvf   = (float*)alloc(512 * 4);
    float*  bqf   = (float*)alloc(512 * 4);
    float*  bmelf = (float*)alloc(1280 * 4);
    ushort* WkT   = (ushort*)alloc((size_t)512 * 512 * 2);
    ushort* WvT   = (ushort*)alloc((size_t)512 * 512 * 2);
    ushort* WqT   = (ushort*)alloc((size_t)512 * 2560 * 2);
    ushort* WmelT = (ushort*)alloc((size_t)1280 * 512 * 2);
    ushort* qval  = (ushort*)alloc((size_t)16 * 2048 * 512 * 2);  // q, then val

    // ---- d_out arena ----
    char* dob = (char*)d_out;
    ushort* phb = (ushort*)dob;                          // [16][1024][512]
    ushort* kbf = (ushort*)(dob + 16777216);             // [16][1024][512]
    ushort* vT  = (ushort*)(dob + 33554432);             // [16][512][1024]
    ushort* sc  = (ushort*)(dob + 50331648);             // [16][2048][1024]

    sniff_dtype<<<1, 64, 0, stream>>>((const uint32_t*)ph, flag);

    // prep: weight transposes + bias/ph conversions
    transpose_cvt<<<dim3(16, 16, 1), 256, 0, stream>>>(Wk, WkT, 512, 512, 0, 0, flag);
    transpose_cvt<<<dim3(16, 16, 1), 256, 0, stream>>>(Wv, WvT, 512, 512, 0, 0, flag);
    transpose_cvt<<<dim3(16, 80, 1), 256, 0, stream>>>(Wq, WqT, 2560, 512, 0, 0, flag);
    transpose_cvt<<<dim3(40, 16, 1), 256, 0, stream>>>(Wmel, WmelT, 512, 1280, 0, 0, flag);
    cvt_bias<<<2, 256, 0, stream>>>(bk, bkf, 512, flag);
    cvt_bias<<<2, 256, 0, stream>>>(bv, bvf, 512, flag);
    cvt_bias<<<2, 256, 0, stream>>>(bq, bqf, 512, flag);
    cvt_bias<<<5, 256, 0, stream>>>(bmel, bmelf, 1280, flag);
    cvt_bf16<<<4096, 256, 0, stream>>>(ph, phb, 1048576, flag);

    // q[b][t][d] = g[b][:,t] . Wq[:,d] + bq  — fused transpose+GEMM v2
    qproj_fused2<<<dim3(2, 16, 16), 256, 0, stream>>>(g, WqT, qval, bqf, flag);

    // k[b][s][d] = ph_bf @ WkT^T + bk
    mfma_gemm<0><<<dim3(4, 8, 16), dim3(256), 0, stream>>>(
        phb, WkT, kbf, bkf, 1024, 512, 512,
        1024L * 512, 0, 1024L * 512, 512, 1.f);
    // vT[b][d][s] = (ph_bf @ WvT^T + bv)^T
    mfma_gemm<1><<<dim3(4, 8, 16), dim3(256), 0, stream>>>(
        phb, WvT, vT, bvf, 1024, 512, 512,
        1024L * 512, 0, 512L * 1024, 1024, 1.f);

    // sc[b][t][s] = q @ k^T / sqrt(512)
    mfma_gemm<0><<<dim3(8, 16, 16), dim3(256), 0, stream>>>(
        qval, kbf, sc, nullptr, 2048, 1024, 512,
        2048L * 512, 1024L * 512, 2048L * 1024, 1024, 0.044194173824159216f);

    softmax_mask<<<dim3(2048, 16), 256, 0, stream>>>(sc, len);

    // val[b][t][d] = P @ vT^T — overwrites dead q
    mfma_gemm<0><<<dim3(4, 16, 16), dim3(256), 0, stream>>>(
        sc, vT, qval, nullptr, 2048, 512, 1024,
        2048L * 1024, 512L * 1024, 2048L * 512, 512, 1.f);

    // out[b][n&63][n>>6][t] = val @ WmelT^T + bmel  (fp32 final)
    mfma_gemm<2><<<dim3(10, 16, 16), dim3(256), 0, stream>>>(
        qval, WmelT, out, bmelf, 2048, 1280, 512,
        2048L * 512, 0, 64L * 20 * 2048, 0, 1.f);
}